// Round 5
// baseline (437.243 us; speedup 1.0000x reference)
//
#include <hip/hip_runtime.h>
#include <climits>
#include <cstdint>

#define L 1000        // NUM_LABELS
#define NROWS 32768   // 64*512

// ws layout (int32 units):
//   [0,    1000)   first_row[label]  (INT_MAX if unseen)
//   [1024, 2048)   evt_g[rank] = (lab<<10)|m   -- compacted, rank-indexed
//   [2048, 3048)   perm_g[pos]

__global__ void k_init(int* __restrict__ first_row) {
    int i = blockIdx.x * blockDim.x + threadIdx.x;
    if (i < L) first_row[i] = INT_MAX;
}

__global__ void k_first(const int* __restrict__ labels, int* __restrict__ first_row) {
    int i = blockIdx.x * blockDim.x + threadIdx.x;
    if (i < NROWS) atomicMin(&first_row[labels[i]], i);
}

// One block per label: argmax of the first-occurrence row (first-index tiebreak)
// AND the event's rank = #{labels with smaller first_row}. Writes evt_g
// directly compacted in row order.
__global__ void k_argmax(const float* __restrict__ flat, const int* __restrict__ first_row,
                         int* __restrict__ evt_g) {
    int lab = blockIdx.x;
    int row = first_row[lab];
    if (row >= NROWS) return;                 // label absent (block-uniform)
    const float* y = flat + (size_t)row * L;
    int tid = threadIdx.x;
    float bv = -INFINITY;
    int bk = 0x7fffffff;
    for (int k = tid; k < L; k += 256) {
        float v = y[k];
        if (v > bv) { bv = v; bk = k; }       // ascending k => strict > keeps first
    }
    int cnt = 0;                              // rank partial (first_row is L2-hot)
    for (int j = tid; j < L; j += 256) cnt += (first_row[j] < row) ? 1 : 0;
    __shared__ float sv[256];
    __shared__ int   sk[256];
    __shared__ int   sc[256];
    sv[tid] = bv; sk[tid] = bk; sc[tid] = cnt;
    __syncthreads();
    for (int off = 128; off > 0; off >>= 1) {
        if (tid < off) {
            float v2 = sv[tid + off]; int k2 = sk[tid + off];
            if (v2 > sv[tid] || (v2 == sv[tid] && k2 < sk[tid])) { sv[tid] = v2; sk[tid] = k2; }
            sc[tid] += sc[tid + off];
        }
        __syncthreads();
    }
    if (tid == 0) evt_g[sc[0]] = (lab << 10) | sk[0];
}

// Single block. Out-of-order serial replay on thread 0 -- same verified
// schedule as round 4 (passed, absmax=0), but ALL loop DS traffic is inline
// asm with hand-counted lgkmcnt waits. Round 4's 460cy/iter was the
// scalarizer: tid==0 values proven uniform -> SGPR pipeline -> every
// ds_read needed an immediate waitcnt+readfirstlane (VGPR_Count=4 was the
// tell). Here "+v" constraints pin the pipeline in VGPRs and waits are
// explicit and counted, with values routed THROUGH the wait asm so
// consumers are data-dependent on the waited value (avoids the
// hoist-past-waitcnt hazard without sched_barrier).
//
// Per-iter DS issue order (6 ops, all asm volatile => order preserved):
//   op1 W_r(j):   pos[r_j] = Plab_j
//   --- s_waitcnt lgkmcnt(7): all ops older than {prev iter's 6, op1} done
//       => legalizes praw_q (j-2 op6, #newer=7), b1 (8), a1 (9), w3 (11).
//   op2 evt prefetch evt[i+5]
//   op3 W_l(j-1): pos[l_{j-1}] = pr_{j-1} (suppressed -> sink when
//       l_{j-1}==r_j: a semantically-later r-write already landed there)
//   op4 a-read pos[m_{j+3}]   (sees op1/op3: LDS is in-order per wave)
//   op5 b-read pos[l_{j+3}]
//   --- patch chain (pure VALU) finalizes event j+1 from 2-iter-old reads;
//       rare key m_{j+1}==l_j takes a REAL branch (volatile asm inside
//       blocks if-conversion) with lgkmcnt(5) for the 1-iter-old praw.
//   op6 pr-read pos[r_{j+1}]  (raw; l_j's write folded by register
//       recurrence pr_j = (r_j==l_{j-1}) ? pr_{j-1} : raw_j, one iter late)
// Common-path recurrence: register rotation + ~10 csel => ~70-90 cy/iter.
__global__ void __launch_bounds__(1024) k_seq(const int* __restrict__ first_row,
                                              const int* __restrict__ evt_g,
                                              int* __restrict__ perm_g) {
    __shared__ int evt[1008];
    __shared__ int pos[1024];                 // [1000..1023] scratch; 1016 = dummy sink
    int tid = threadIdx.x;
    int present = (tid < L) && (first_row[tid] < NROWS);
    int K = __syncthreads_count(present);     // #events == #present labels
    if (tid < K) evt[tid] = evt_g[tid];
    if (tid >= K && tid < K + 7) evt[tid] = 0;   // pads (m=l=0): read-only, never written back
    if (tid < L) pos[tid] = tid;              // pos = idx_sel^{-1}, initially identity
    __syncthreads();
    if (tid == 0 && K > 0) {
        // LDS byte offsets: generic LDS addr = (aperture<<32)|offset -> low 32 bits
        uint32_t posb = (uint32_t)(uintptr_t)(void*)pos;
        uint32_t evtb = (uint32_t)(uintptr_t)(void*)evt;
        int e0 = evt[0], e1 = evt[1], e2 = evt[2];   // prologue: compiler DS ops,
        int w3 = evt[3], w4 = evt[4];                // fully drained before loop
        int r0 = e0 & 1023, l0 = e0 >> 10;    // event j=0 (identity state)
        int Pl0 = l0, praw = r0;              // Plab_0 = l_0, raw pr_0 = m_0
        int rq = 1017, lq = 1016, Plq = 0;    // event j-1 dummies (never match keys)
        int lqq = 1018, Mprev = 0, praw_q = 0;// event j-2 dummies
        int m1 = e1 & 1023, l1 = e1 >> 10, a1 = m1, b1 = l1;  // identity reads
        int m2 = e2 & 1023, l2 = e2 >> 10, a2 = m2, b2 = l2;
        for (int i = 0; i < K; i++) {
            uint32_t aw1 = posb + ((uint32_t)r0 << 2);           // op1: W_r(j)
            asm volatile("ds_write_b32 %0, %1" :: "v"(aw1), "v"(Pl0));
            // counted wait; waited values routed through as data deps
            asm volatile("s_waitcnt lgkmcnt(7)"
                         : "+v"(praw_q), "+v"(a1), "+v"(b1), "+v"(w3));
            uint32_t ae = evtb + ((uint32_t)(i + 5) << 2);       // op2: evt prefetch
            int wn;
            asm volatile("ds_read_b32 %0, %1" : "=v"(wn) : "v"(ae));
            int Mcur = (rq == lqq) ? Mprev : praw_q;             // pr_{j-1} materialized
            int waddr = (lq == r0) ? 1016 : lq;                  // suppression -> sink
            uint32_t aw2 = posb + ((uint32_t)waddr << 2);        // op3: W_l(j-1)
            asm volatile("ds_write_b32 %0, %1" :: "v"(aw2), "v"(Mcur));
            int m3 = w3 & 1023, l3 = w3 >> 10;                   // event j+3 addrs
            uint32_t ar1 = posb + ((uint32_t)m3 << 2);
            uint32_t ar2 = posb + ((uint32_t)l3 << 2);
            int a3, b3;
            asm volatile("ds_read_b32 %0, %1" : "=v"(a3) : "v"(ar1));  // op4
            asm volatile("ds_read_b32 %0, %1" : "=v"(b3) : "v"(ar2));  // op5
            // finalize event j+1: patch 2-iter-old reads vs missing writes
            // {l_{j-2}, r_{j-1}, l_{j-1}, r_j, l_j} in semantic order
            int r1f = (m1 == lqq) ? Mprev : a1;
            r1f = (m1 == rq) ? Plq : r1f;
            r1f = (m1 == lq) ? Mcur : r1f;
            r1f = (m1 == r0) ? Pl0 : r1f;
            if (m1 == l0) {                                      // RARE (~0.2%/iter)
                asm volatile("s_waitcnt lgkmcnt(5)" : "+v"(praw));
                r1f = (r0 == lq) ? Mcur : praw;                  // pr_j
            }
            int Pl1f = (l1 == rq) ? Plq : b1;                    // b-chain: r-keys only
            Pl1f = (l1 == r0) ? Pl0 : Pl1f;                      // (l/l keys impossible)
            uint32_t ar3 = posb + ((uint32_t)r1f << 2);          // op6: raw pr_{j+1}
            int prawn;
            asm volatile("ds_read_b32 %0, %1" : "=v"(prawn) : "v"(ar3));
            // rotate
            Mprev = Mcur; praw_q = praw;
            lqq = lq; rq = r0; Plq = Pl0; lq = l0;
            r0 = r1f; l0 = l1; Pl0 = Pl1f; praw = prawn;
            m1 = m2; l1 = l2; a1 = a2; b1 = b2;
            m2 = m3; l2 = l3; a2 = a3; b2 = b3;
            w3 = w4; w4 = wn;
        }
        asm volatile("s_waitcnt lgkmcnt(0)" : "+v"(praw_q));
        int Mfin = (rq == lqq) ? Mprev : praw_q;                 // pr_{K-1}
        uint32_t awf = posb + ((uint32_t)lq << 2);
        asm volatile("ds_write_b32 %0, %1" :: "v"(awf), "v"(Mfin)); // final W_l(K-1)
    }
    __syncthreads();                          // drains vm+lgkm incl. our asm writes
    if (tid < L) perm_g[pos[tid]] = tid;      // invert: perm[pos[v]] = v
}

// 4 rows per block IN PARALLEL (four 256-thread groups sharing the p table).
// Global read and write fully coalesced float4; permuted gather goes via LDS.
__global__ void __launch_bounds__(1024) k_gather(const float* __restrict__ flat,
                                                 const int* __restrict__ perm_g,
                                                 float* __restrict__ out) {
    __shared__ __align__(16) int   p[1024];
    __shared__ __align__(16) float buf[4][L];
    int tid = threadIdx.x;
    if (tid < L) p[tid] = perm_g[tid];
    int g = tid >> 8;            // group 0..3 -> row within block
    int t = tid & 255;           // lane-in-group
    size_t row = (size_t)blockIdx.x * 4 + g;
    const float* src = flat + row * L;
    float*       dst = out  + row * L;
    float4 v;
    if (t < 250) v = ((const float4*)src)[t];
    __syncthreads();             // p visible; (v still in flight is fine)
    if (t < 250) ((float4*)buf[g])[t] = v;
    __syncthreads();             // buf visible
    if (t < 250) {
        int j = t * 4;
        float4 o;
        o.x = buf[g][p[j + 0]];
        o.y = buf[g][p[j + 1]];
        o.z = buf[g][p[j + 2]];
        o.w = buf[g][p[j + 3]];
        ((float4*)dst)[t] = o;
    }
}

extern "C" void kernel_launch(void* const* d_in, const int* in_sizes, int n_in,
                              void* d_out, int out_size, void* d_ws, size_t ws_size,
                              hipStream_t stream) {
    const float* flat   = (const float*)d_in[0];   // (64,512,1000) fp32
    const int*   labels = (const int*)d_in[1];     // (64,512) int32
    float* out = (float*)d_out;
    int* ws = (int*)d_ws;
    int* first_row = ws;          // 1000
    int* evt_g     = ws + 1024;   // 1000 (rank-compacted events)
    int* perm_g    = ws + 2048;   // 1000

    k_init  <<<(L + 255) / 256, 256, 0, stream>>>(first_row);
    k_first <<<(NROWS + 255) / 256, 256, 0, stream>>>(labels, first_row);
    k_argmax<<<L, 256, 0, stream>>>(flat, first_row, evt_g);
    k_seq   <<<1, 1024, 0, stream>>>(first_row, evt_g, perm_g);
    k_gather<<<NROWS / 4, 1024, 0, stream>>>(flat, perm_g, out);
}